// Round 3
// baseline (836.703 us; speedup 1.0000x reference)
//
#include <hip/hip_runtime.h>
#include <hip/hip_cooperative_groups.h>
#include <hip/hip_fp16.h>
#include <stdint.h>
#include <stddef.h>

namespace cg = cooperative_groups;

#define N_NODES   40000
#define N_EDGES   640000
#define IN_FEATS  256
#define EDGE_FEATS 64
#define OUT_FEATS 128
#define NUM_HEADS 8
#define HD        16   // per-head dim

#define SCAN_BLOCKS 157   // ceil(40000/256)

typedef __attribute__((ext_vector_type(8))) short  short8;   // 8 x bf16 bits
typedef __attribute__((ext_vector_type(4))) float  floatx4;

__device__ inline short f2bf(float f) {
  union { float f; uint32_t u; } v; v.f = f;
  uint32_t r = v.u + 0x7fffu + ((v.u >> 16) & 1u);   // RNE
  return (short)(r >> 16);
}

__device__ inline short8 cvt8(float4 lo, float4 hi) {
  short8 r;
  r[0] = f2bf(lo.x); r[1] = f2bf(lo.y); r[2] = f2bf(lo.z); r[3] = f2bf(lo.w);
  r[4] = f2bf(hi.x); r[5] = f2bf(hi.y); r[6] = f2bf(hi.z); r[7] = f2bf(hi.w);
  return r;
}

__device__ inline float bflo(uint32_t w) {
  union { uint32_t u; float f; } v; v.u = w << 16; return v.f;
}
__device__ inline float bfhi(uint32_t w) {
  union { uint32_t u; float f; } v; v.u = w & 0xffff0000u; return v.f;
}

// ---------------- K1: prep (block 0: fold + W->bf16) + dst histogram
__global__ __launch_bounds__(512) void prep_hist_kernel(
    const float* __restrict__ edge_w, const float* __restrict__ edge_b,
    const float* __restrict__ attn, const float* __restrict__ node_w,
    const int* __restrict__ dst,
    float* __restrict__ Wfold, float* __restrict__ bfold,
    uint32_t* __restrict__ Wbf, int* __restrict__ deg) {
  int tid = threadIdx.x;
  if (blockIdx.x == 0) {
    int h = tid >> 6, k = tid & 63;
    float s = 0.f;
    #pragma unroll
    for (int d = 0; d < HD; d++)
      s += edge_w[(h * HD + d) * EDGE_FEATS + k] * attn[h * 48 + 32 + d];
    Wfold[h * EDGE_FEATS + k] = s;
    if (k == 0) {
      float b = 0.f;
      #pragma unroll
      for (int d = 0; d < HD; d++)
        b += edge_b[h * HD + d] * attn[h * 48 + 32 + d];
      bfold[h] = b;
    }
    const float2* W2 = (const float2*)node_w;
    #pragma unroll
    for (int j = 0; j < 32; j++) {
      int p = j * 512 + tid;
      float2 f = W2[p];
      Wbf[p] = (uint32_t)(uint16_t)f2bf(f.x) |
               ((uint32_t)(uint16_t)f2bf(f.y) << 16);
    }
  } else {
    int e = (blockIdx.x - 1) * 512 + tid;   // 1250 blocks * 512 = 640000
    atomicAdd(&deg[dst[e]], 1);
  }
}

// ---------------- K2: Whp (packed bf16) = node_feats @ node_w^T + node_b
__global__ __launch_bounds__(256) void wh_gemm(
    const float* __restrict__ A,       // node_feats [40000][256]
    const uint32_t* __restrict__ Wbf,  // node_w bf16-packed [128][256]
    const float* __restrict__ bias,    // node_b [128]
    uint32_t* __restrict__ Whp) {      // [40000][64] packed
  int wave = (blockIdx.x * blockDim.x + threadIdx.x) >> 6;
  int lane = threadIdx.x & 63;
  int m0 = wave * 16;
  if (m0 >= N_NODES) return;
  int row = lane & 15, quad = lane >> 4;

  floatx4 acc[8];
  #pragma unroll
  for (int nt = 0; nt < 8; nt++) acc[nt] = (floatx4)(0.f);

  const float4* A4 = (const float4*)A;
  const uint4*  W4 = (const uint4*)Wbf;
  int a_base = ((m0 + row) * IN_FEATS + quad * 8) >> 2;   // float4 units

  #pragma unroll
  for (int s = 0; s < 8; s++) {
    float4 alo = A4[a_base + s * 8];
    float4 ahi = A4[a_base + s * 8 + 1];
    short8 af = cvt8(alo, ahi);
    #pragma unroll
    for (int nt = 0; nt < 8; nt++) {
      int fo = (nt * 16 + row) * IN_FEATS + s * 32 + quad * 8;
      uint4 u = W4[fo >> 3];
      short8 bf = *(short8*)&u;
      acc[nt] = __builtin_amdgcn_mfma_f32_16x16x32_bf16(af, bf, acc[nt], 0, 0, 0);
    }
  }
  #pragma unroll
  for (int nt = 0; nt < 4; nt++) {
    float blo_ = bias[nt * 16 + row];
    float bhi_ = bias[64 + nt * 16 + row];
    #pragma unroll
    for (int r = 0; r < 4; r++) {
      int m = m0 + quad * 4 + r;
      float lo = acc[nt][r] + blo_;
      float hi = acc[nt + 4][r] + bhi_;
      uint32_t d = (uint32_t)(uint16_t)f2bf(lo) |
                   ((uint32_t)(uint16_t)f2bf(hi) << 16);
      Whp[m * 64 + nt * 16 + row] = d;
    }
  }
}

// ---------------- K3 (cooperative): ssd + scan + edge_scatter + aggregate
// Phases separated by grid.sync(); all loops grid-strided.
__global__ __launch_bounds__(256, 2) void fused_tail_kernel(
    const uint32_t* __restrict__ Whp, const float* __restrict__ attn,
    float* __restrict__ s_src, float* __restrict__ s_dst,
    const int* __restrict__ deg, int* __restrict__ rs,
    int* __restrict__ cursor, int* __restrict__ bsum, int* __restrict__ bsx,
    const float* __restrict__ edge_feats, const int* __restrict__ src,
    const int* __restrict__ dst, const float* __restrict__ Wfold,
    const float* __restrict__ bfold, int* __restrict__ csrc,
    uint4* __restrict__ clg, float* __restrict__ out) {
  cg::grid_group grid = cg::this_grid();
  __shared__ float4 efs[16 * 256];          // 64 KB: [k4][edge ^ (k4&7)]
  __shared__ int wtot[4];
  int tid = threadIdx.x, bid = blockIdx.x;
  int lane = tid & 63, w = tid >> 6;
  int gstride = gridDim.x * 256;

  // ---- P1a: s_src / s_dst from packed Whp (grid-stride over 160000 items)
  for (int t = bid * 256 + tid; t < N_NODES * 4; t += gstride) {
    int n = t >> 2, hp = t & 3;             // head pair (hp, hp+4)
    const uint4* p = (const uint4*)(Whp + n * 64 + hp * 16);
    const float* as_lo = attn + hp * 48;
    const float* ad_lo = attn + hp * 48 + 16;
    const float* as_hi = attn + (hp + 4) * 48;
    const float* ad_hi = attn + (hp + 4) * 48 + 16;
    float ss_lo = 0.f, sd_lo = 0.f, ss_hi = 0.f, sd_hi = 0.f;
    #pragma unroll
    for (int q = 0; q < 4; q++) {
      uint4 u = p[q];
      uint32_t ws_[4] = {u.x, u.y, u.z, u.w};
      #pragma unroll
      for (int k = 0; k < 4; k++) {
        int dd = q * 4 + k;
        float lo = bflo(ws_[k]), hi = bfhi(ws_[k]);
        ss_lo += lo * as_lo[dd]; sd_lo += lo * ad_lo[dd];
        ss_hi += hi * as_hi[dd]; sd_hi += hi * ad_hi[dd];
      }
    }
    s_src[n * 8 + hp]     = ss_lo;
    s_src[n * 8 + hp + 4] = ss_hi;
    s_dst[n * 8 + hp]     = sd_lo;
    s_dst[n * 8 + hp + 4] = sd_hi;
  }

  // ---- P1b: scan stage 1 — per-block exclusive prefix + block totals
  int lex = 0;
  if (bid < SCAN_BLOCKS) {
    int i = bid * 256 + tid;
    int v = (i < N_NODES) ? deg[i] : 0;
    int x = v;
    #pragma unroll
    for (int off = 1; off < 64; off <<= 1) {
      int y = __shfl_up(x, off, 64);
      if (lane >= off) x += y;
    }
    if (lane == 63) wtot[w] = x;
    __syncthreads();
    int pre = 0, tot = 0;
    #pragma unroll
    for (int j = 0; j < 4; j++) { int sj = wtot[j]; if (j < w) pre += sj; tot += sj; }
    lex = pre + x - v;
    if (tid == 0) bsum[bid] = tot;
    __syncthreads();
  }
  __threadfence();
  grid.sync();

  // ---- P2: block 0 scans the 157 block totals (exclusive)
  if (bid == 0) {
    int v = (tid < SCAN_BLOCKS) ? bsum[tid] : 0;
    int x = v;
    #pragma unroll
    for (int off = 1; off < 64; off <<= 1) {
      int y = __shfl_up(x, off, 64);
      if (lane >= off) x += y;
    }
    if (lane == 63) wtot[w] = x;
    __syncthreads();
    int pre = 0;
    #pragma unroll
    for (int j = 0; j < 4; j++) { int sj = wtot[j]; if (j < w) pre += sj; }
    int ex2 = pre + x - v;
    if (tid < SCAN_BLOCKS) bsx[tid] = ex2;
    if (tid == SCAN_BLOCKS - 1) rs[N_NODES] = ex2 + v;
    __syncthreads();
  }
  __threadfence();
  grid.sync();

  // ---- P3: finalize rs / cursor
  if (bid < SCAN_BLOCKS) {
    int i = bid * 256 + tid;
    if (i < N_NODES) {
      int e0 = lex + bsx[bid];
      rs[i] = e0;
      cursor[i] = e0;
    }
  }
  __threadfence();
  grid.sync();

  // ---- P4: per-edge logits + scatter into CSR order (grid-stride tiles)
  float bf_[8];
  #pragma unroll
  for (int h = 0; h < 8; h++) bf_[h] = bfold[h];
  for (int tile = bid; tile < N_EDGES / 256; tile += gridDim.x) {
    int e0 = tile * 256;
    int e = e0 + tid;
    int se = src[e], de = dst[e];
    int pos = atomicAdd(&cursor[de], 1);    // early: latency overlaps staging

    const float4* ss4 = (const float4*)(s_src + (size_t)se * 8);
    const float4* sd4 = (const float4*)(s_dst + (size_t)de * 8);
    float4 sa = ss4[0], sb = ss4[1];
    float4 da = sd4[0], db = sd4[1];

    __syncthreads();                        // prior tile's efs reads done
    const float4* base = (const float4*)(edge_feats + (size_t)e0 * EDGE_FEATS);
    #pragma unroll
    for (int j = 0; j < 16; j++) {
      int p = j * 256 + tid;                // linear float4 index, coalesced
      float4 vv = base[p];
      int k4 = p & 15;
      int edge = p >> 4;
      efs[k4 * 256 + (edge ^ (k4 & 7))] = vv;
    }
    __syncthreads();

    float acc[8];
    #pragma unroll
    for (int h = 0; h < 8; h++) acc[h] = bf_[h];
    #pragma unroll
    for (int k4 = 0; k4 < 16; k4++) {
      float4 f = efs[k4 * 256 + (tid ^ (k4 & 7))];
      #pragma unroll
      for (int h = 0; h < 8; h++) {
        const float* wr = Wfold + h * EDGE_FEATS + k4 * 4;  // wave-uniform
        acc[h] += f.x * wr[0] + f.y * wr[1] + f.z * wr[2] + f.w * wr[3];
      }
    }
    float v[8];
    v[0] = acc[0] + sa.x + da.x; v[1] = acc[1] + sa.y + da.y;
    v[2] = acc[2] + sa.z + da.z; v[3] = acc[3] + sa.w + da.w;
    v[4] = acc[4] + sb.x + db.x; v[5] = acc[5] + sb.y + db.y;
    v[6] = acc[6] + sb.z + db.z; v[7] = acc[7] + sb.w + db.w;
    #pragma unroll
    for (int h = 0; h < 8; h++) v[h] = v[h] > 0.f ? v[h] : 0.2f * v[h];

    uint32_t pk[4];
    #pragma unroll
    for (int j = 0; j < 4; j++) {
      uint32_t lo = __half_as_ushort(__float2half_rn(v[2 * j]));
      uint32_t hi = __half_as_ushort(__float2half_rn(v[2 * j + 1]));
      pk[j] = lo | (hi << 16);
    }
    csrc[pos] = se;
    clg[pos] = make_uint4(pk[0], pk[1], pk[2], pk[3]);
  }
  __threadfence();
  grid.sync();

  // ---- P5: per-node softmax (no-max exp) + aggregation (grid-stride)
  for (int grp = bid; grp < N_NODES / 4; grp += gridDim.x) {
    int node = grp * 4 + w;
    int h1 = lane >> 4;
    int start = rs[node], end = rs[node + 1];
    uint32_t sh = (h1 & 1) * 16;
    bool hi_pair = (h1 & 2) != 0;

    float z1 = 0.f, z2 = 0.f, a1 = 0.f, a2 = 0.f;

    #define STEP(g, wv)                                                  \
      {                                                                  \
        uint32_t c1 = hi_pair ? (g).y : (g).x;                           \
        uint32_t c2 = hi_pair ? (g).w : (g).z;                           \
        float l1 = __half2float(__ushort_as_half((uint16_t)(c1 >> sh))); \
        float l2 = __half2float(__ushort_as_half((uint16_t)(c2 >> sh))); \
        float e1 = __expf(l1), e2 = __expf(l2);                          \
        z1 += e1; z2 += e2;                                              \
        a1 += e1 * bflo(wv); a2 += e2 * bfhi(wv);                        \
      }

    int i = start;
    for (; i + 3 < end; i += 4) {
      int s0 = csrc[i], s1 = csrc[i + 1], s2 = csrc[i + 2], s3 = csrc[i + 3];
      uint4 g0 = clg[i], g1 = clg[i + 1], g2 = clg[i + 2], g3 = clg[i + 3];
      uint32_t w0 = Whp[(size_t)s0 * 64 + lane];
      uint32_t w1 = Whp[(size_t)s1 * 64 + lane];
      uint32_t w2 = Whp[(size_t)s2 * 64 + lane];
      uint32_t w3 = Whp[(size_t)s3 * 64 + lane];
      STEP(g0, w0); STEP(g1, w1); STEP(g2, w2); STEP(g3, w3);
    }
    for (; i < end; i++) {
      int s0 = csrc[i];
      uint4 g0 = clg[i];
      uint32_t w0 = Whp[(size_t)s0 * 64 + lane];
      STEP(g0, w0);
    }
    #undef STEP

    float o1 = (end > start) ? a1 / z1 : 0.f;
    float o2 = (end > start) ? a2 / z2 : 0.f;
    out[(size_t)node * OUT_FEATS + lane] = o1;
    out[(size_t)node * OUT_FEATS + 64 + lane] = o2;
  }
}

extern "C" void kernel_launch(void* const* d_in, const int* in_sizes, int n_in,
                              void* d_out, int out_size, void* d_ws, size_t ws_size,
                              hipStream_t stream) {
  const float* node_feats = (const float*)d_in[0];
  const float* edge_feats = (const float*)d_in[1];
  const int*   src        = (const int*)d_in[2];
  const int*   dst        = (const int*)d_in[3];
  const float* node_w     = (const float*)d_in[4];
  const float* node_b     = (const float*)d_in[5];
  const float* edge_w     = (const float*)d_in[6];
  const float* edge_b     = (const float*)d_in[7];
  const float* attn       = (const float*)d_in[8];
  float* out = (float*)d_out;

  char* ws = (char*)d_ws;
  size_t off = 0;
  auto alloc = [&](size_t bytes) {
    void* p = ws + off;
    off += (bytes + 255) & ~(size_t)255;
    return p;
  };
  uint32_t* Whp      = (uint32_t*)alloc((size_t)N_NODES * 64 * 4);      // 10.24 MB
  float*    s_src    = (float*)alloc((size_t)N_NODES * NUM_HEADS * 4);  // 1.28 MB
  float*    s_dst    = (float*)alloc((size_t)N_NODES * NUM_HEADS * 4);  // 1.28 MB
  int*      csrc     = (int*)alloc((size_t)N_EDGES * 4);                // 2.56 MB
  uint4*    clg      = (uint4*)alloc((size_t)N_EDGES * 16);             // 10.24 MB
  int*      deg      = (int*)alloc((size_t)N_NODES * 4);
  int*      rs       = (int*)alloc((size_t)(N_NODES + 1) * 4);
  int*      cursor   = (int*)alloc((size_t)N_NODES * 4);
  int*      bsum     = (int*)alloc(256 * 4);
  int*      bsx      = (int*)alloc(256 * 4);
  float*    Wfold    = (float*)alloc(NUM_HEADS * EDGE_FEATS * 4);
  float*    bfold    = (float*)alloc(NUM_HEADS * 4);
  uint32_t* Wbf      = (uint32_t*)alloc((size_t)OUT_FEATS * IN_FEATS * 2); // 64 KB

  hipMemsetAsync(deg, 0, (size_t)N_NODES * 4, stream);

  prep_hist_kernel<<<1 + N_EDGES / 512, 512, 0, stream>>>(
      edge_w, edge_b, attn, node_w, dst, Wfold, bfold, Wbf, deg);
  wh_gemm<<<N_NODES / 16 / 4, 256, 0, stream>>>(node_feats, Wbf, node_b, Whp);

  // cooperative tail: grid sized for guaranteed co-residency
  int maxb = 0;
  hipOccupancyMaxActiveBlocksPerMultiprocessor(&maxb, fused_tail_kernel, 256, 0);
  if (maxb < 1) maxb = 1;
  int grid = maxb * 256;          // 256 CUs
  if (grid > 512) grid = 512;     // 2 blocks/CU is the LDS cap anyway
  if (grid < SCAN_BLOCKS) grid = SCAN_BLOCKS;  // scan stage 1 requirement

  void* args[] = {
    (void*)&Whp, (void*)&attn, (void*)&s_src, (void*)&s_dst,
    (void*)&deg, (void*)&rs, (void*)&cursor, (void*)&bsum, (void*)&bsx,
    (void*)&edge_feats, (void*)&src, (void*)&dst, (void*)&Wfold,
    (void*)&bfold, (void*)&csrc, (void*)&clg, (void*)&out
  };
  hipLaunchCooperativeKernel(fused_tail_kernel, dim3(grid), dim3(256),
                             args, 0, stream);
}

// Round 4
// 409.057 us; speedup vs baseline: 2.0454x; 2.0454x over previous
//
#include <hip/hip_runtime.h>
#include <hip/hip_fp16.h>
#include <stdint.h>
#include <stddef.h>

#define N_NODES   40000
#define N_EDGES   640000
#define IN_FEATS  256
#define EDGE_FEATS 64
#define OUT_FEATS 128
#define NUM_HEADS 8
#define HD        16   // per-head dim

typedef __attribute__((ext_vector_type(8))) short  short8;   // 8 x bf16 bits
typedef __attribute__((ext_vector_type(4))) float  floatx4;

__device__ inline short f2bf(float f) {
  union { float f; uint32_t u; } v; v.f = f;
  uint32_t r = v.u + 0x7fffu + ((v.u >> 16) & 1u);   // RNE
  return (short)(r >> 16);
}

__device__ inline short8 cvt8(float4 lo, float4 hi) {
  short8 r;
  r[0] = f2bf(lo.x); r[1] = f2bf(lo.y); r[2] = f2bf(lo.z); r[3] = f2bf(lo.w);
  r[4] = f2bf(hi.x); r[5] = f2bf(hi.y); r[6] = f2bf(hi.z); r[7] = f2bf(hi.w);
  return r;
}

__device__ inline float bflo(uint32_t w) {
  union { uint32_t u; float f; } v; v.u = w << 16; return v.f;
}
__device__ inline float bfhi(uint32_t w) {
  union { uint32_t u; float f; } v; v.u = w & 0xffff0000u; return v.f;
}

// ---------------- K1: prep (block 0: fold + W->bf16) + dst histogram
__global__ __launch_bounds__(512) void prep_hist_kernel(
    const float* __restrict__ edge_w, const float* __restrict__ edge_b,
    const float* __restrict__ attn, const float* __restrict__ node_w,
    const int* __restrict__ dst,
    float* __restrict__ Wfold, float* __restrict__ bfold,
    uint32_t* __restrict__ Wbf, int* __restrict__ deg) {
  int tid = threadIdx.x;
  if (blockIdx.x == 0) {
    int h = tid >> 6, k = tid & 63;
    float s = 0.f;
    #pragma unroll
    for (int d = 0; d < HD; d++)
      s += edge_w[(h * HD + d) * EDGE_FEATS + k] * attn[h * 48 + 32 + d];
    Wfold[h * EDGE_FEATS + k] = s;
    if (k == 0) {
      float b = 0.f;
      #pragma unroll
      for (int d = 0; d < HD; d++)
        b += edge_b[h * HD + d] * attn[h * 48 + 32 + d];
      bfold[h] = b;
    }
    const float2* W2 = (const float2*)node_w;
    #pragma unroll
    for (int j = 0; j < 32; j++) {
      int p = j * 512 + tid;
      float2 f = W2[p];
      Wbf[p] = (uint32_t)(uint16_t)f2bf(f.x) |
               ((uint32_t)(uint16_t)f2bf(f.y) << 16);
    }
  } else {
    int e = (blockIdx.x - 1) * 512 + tid;   // 1250 blocks * 512 = 640000
    atomicAdd(&deg[dst[e]], 1);
  }
}

// ---------------- K2: Whp (packed bf16) = node_feats @ node_w^T + node_b
__global__ __launch_bounds__(256) void wh_gemm(
    const float* __restrict__ A,       // node_feats [40000][256]
    const uint32_t* __restrict__ Wbf,  // node_w bf16-packed [128][256]
    const float* __restrict__ bias,    // node_b [128]
    uint32_t* __restrict__ Whp) {      // [40000][64] packed
  int wave = (blockIdx.x * blockDim.x + threadIdx.x) >> 6;
  int lane = threadIdx.x & 63;
  int m0 = wave * 16;
  if (m0 >= N_NODES) return;
  int row = lane & 15, quad = lane >> 4;

  floatx4 acc[8];
  #pragma unroll
  for (int nt = 0; nt < 8; nt++) acc[nt] = (floatx4)(0.f);

  const float4* A4 = (const float4*)A;
  const uint4*  W4 = (const uint4*)Wbf;
  int a_base = ((m0 + row) * IN_FEATS + quad * 8) >> 2;   // float4 units

  #pragma unroll
  for (int s = 0; s < 8; s++) {
    float4 alo = A4[a_base + s * 8];
    float4 ahi = A4[a_base + s * 8 + 1];
    short8 af = cvt8(alo, ahi);
    #pragma unroll
    for (int nt = 0; nt < 8; nt++) {
      int fo = (nt * 16 + row) * IN_FEATS + s * 32 + quad * 8;
      uint4 u = W4[fo >> 3];
      short8 bf = *(short8*)&u;
      acc[nt] = __builtin_amdgcn_mfma_f32_16x16x32_bf16(af, bf, acc[nt], 0, 0, 0);
    }
  }
  #pragma unroll
  for (int nt = 0; nt < 4; nt++) {
    float blo_ = bias[nt * 16 + row];
    float bhi_ = bias[64 + nt * 16 + row];
    #pragma unroll
    for (int r = 0; r < 4; r++) {
      int m = m0 + quad * 4 + r;
      float lo = acc[nt][r] + blo_;
      float hi = acc[nt + 4][r] + bhi_;
      uint32_t d = (uint32_t)(uint16_t)f2bf(lo) |
                   ((uint32_t)(uint16_t)f2bf(hi) << 16);
      Whp[m * 64 + nt * 16 + row] = d;
    }
  }
}

// ---------------- K3: s_src[n][h], s_dst[n][h] from packed Whp
__global__ __launch_bounds__(256) void ssd_kernel(
    const uint32_t* __restrict__ Whp, const float* __restrict__ attn,
    float* __restrict__ s_src, float* __restrict__ s_dst) {
  int t = blockIdx.x * 256 + threadIdx.x;   // exact 160000 = 40000*4
  int n = t >> 2, hp = t & 3;               // head pair (hp, hp+4)
  const uint4* p = (const uint4*)(Whp + n * 64 + hp * 16);
  const float* as_lo = attn + hp * 48;
  const float* ad_lo = attn + hp * 48 + 16;
  const float* as_hi = attn + (hp + 4) * 48;
  const float* ad_hi = attn + (hp + 4) * 48 + 16;
  float ss_lo = 0.f, sd_lo = 0.f, ss_hi = 0.f, sd_hi = 0.f;
  #pragma unroll
  for (int q = 0; q < 4; q++) {
    uint4 u = p[q];
    uint32_t ws[4] = {u.x, u.y, u.z, u.w};
    #pragma unroll
    for (int k = 0; k < 4; k++) {
      int d = q * 4 + k;
      float lo = bflo(ws[k]), hi = bfhi(ws[k]);
      ss_lo += lo * as_lo[d]; sd_lo += lo * ad_lo[d];
      ss_hi += hi * as_hi[d]; sd_hi += hi * ad_hi[d];
    }
  }
  s_src[n * 8 + hp]     = ss_lo;
  s_src[n * 8 + hp + 4] = ss_hi;
  s_dst[n * 8 + hp]     = sd_lo;
  s_dst[n * 8 + hp + 4] = sd_hi;
}

// ---------------- K4: register-staged single-barrier exclusive scan
// 1 block x 1024 threads; 40 chunks of 1024 preloaded into registers.
__global__ __launch_bounds__(1024) void scan_kernel(
    const int* __restrict__ deg, int* __restrict__ rs, int* __restrict__ cursor) {
  __shared__ int wsum[40][16];
  int tid = threadIdx.x;
  int lane = tid & 63, w = tid >> 6;

  int ex[40];   // exclusive-within-wave prefix per chunk (static indexing only)
  #pragma unroll
  for (int c = 0; c < 40; c++) {
    int i = c * 1024 + tid;
    int vv = (i < N_NODES) ? deg[i] : 0;
    int xv = vv;
    #pragma unroll
    for (int off = 1; off < 64; off <<= 1) {
      int y = __shfl_up(xv, off, 64);
      if (lane >= off) xv += y;
    }
    ex[c] = xv - vv;
    if (lane == 63) wsum[c][w] = xv;
  }
  __syncthreads();   // the only barrier

  int carry = 0;     // computed redundantly & identically by every thread
  #pragma unroll
  for (int c = 0; c < 40; c++) {
    int p = carry;
    #pragma unroll
    for (int j = 0; j < 16; j++) {
      int s = wsum[c][j];   // uniform address -> LDS broadcast
      if (j < w) p += s;
      carry += s;
    }
    int i = c * 1024 + tid;
    if (i < N_NODES) {
      int excl = p + ex[c];
      rs[i] = excl;
      cursor[i] = excl;
    }
  }
  if (tid == 0) rs[N_NODES] = carry;
}

// ---------------- K5: fused per-edge logits + scatter into CSR order
// Coalesced global read -> LDS transpose (XOR bank swizzle), then per-edge
// GEMV from LDS. Scatter writes ONE 32-byte record per edge
// {8 x half logits, src, pad} -> single scattered cache-line touch per edge
// (was two: csrc 4B + clg 16B in different arrays).
__global__ __launch_bounds__(256) void edge_scatter_kernel(
    const float* __restrict__ edge_feats, const int* __restrict__ src,
    const int* __restrict__ dst, const float* __restrict__ Wfold,
    const float* __restrict__ bfold, const float* __restrict__ s_src,
    const float* __restrict__ s_dst, int* __restrict__ cursor,
    uint32_t* __restrict__ rec) {   // rec: [N_EDGES][8] u32 (32 B records)
  __shared__ float4 efs[16 * 256];          // 64 KB: [k4][edge ^ (k4&7)]
  int tid = threadIdx.x;
  int e0 = blockIdx.x * 256;
  int e = e0 + tid;
  int s = src[e], d = dst[e];
  int pos = atomicAdd(&cursor[d], 1);       // issue early: latency overlaps load

  const float4* ss4 = (const float4*)(s_src + (size_t)s * 8);
  const float4* sd4 = (const float4*)(s_dst + (size_t)d * 8);
  float4 sa = ss4[0], sb = ss4[1];
  float4 da = sd4[0], db = sd4[1];

  // cooperative coalesced load + LDS transpose
  const float4* base = (const float4*)(edge_feats + (size_t)e0 * EDGE_FEATS);
  #pragma unroll
  for (int j = 0; j < 16; j++) {
    int p = j * 256 + tid;                  // linear float4 index, coalesced
    float4 v = base[p];
    int k4 = p & 15;
    int edge = p >> 4;
    efs[k4 * 256 + (edge ^ (k4 & 7))] = v;  // XOR swizzle: balanced banks
  }
  __syncthreads();

  float acc[8];
  #pragma unroll
  for (int h = 0; h < 8; h++) acc[h] = bfold[h];
  #pragma unroll
  for (int k4 = 0; k4 < 16; k4++) {
    float4 f = efs[k4 * 256 + (tid ^ (k4 & 7))];
    #pragma unroll
    for (int h = 0; h < 8; h++) {
      const float* wr = Wfold + h * EDGE_FEATS + k4 * 4;  // wave-uniform
      acc[h] += f.x * wr[0] + f.y * wr[1] + f.z * wr[2] + f.w * wr[3];
    }
  }
  float v[8];
  v[0] = acc[0] + sa.x + da.x; v[1] = acc[1] + sa.y + da.y;
  v[2] = acc[2] + sa.z + da.z; v[3] = acc[3] + sa.w + da.w;
  v[4] = acc[4] + sb.x + db.x; v[5] = acc[5] + sb.y + db.y;
  v[6] = acc[6] + sb.z + db.z; v[7] = acc[7] + sb.w + db.w;
  #pragma unroll
  for (int h = 0; h < 8; h++) v[h] = v[h] > 0.f ? v[h] : 0.2f * v[h];

  uint32_t pk[4];
  #pragma unroll
  for (int j = 0; j < 4; j++) {
    uint32_t lo = __half_as_ushort(__float2half_rn(v[2 * j]));
    uint32_t hi = __half_as_ushort(__float2half_rn(v[2 * j + 1]));
    pk[j] = lo | (hi << 16);
  }
  uint32_t* r = rec + (size_t)pos * 8;
  *(uint4*)r = make_uint4(pk[0], pk[1], pk[2], pk[3]);
  r[4] = (uint32_t)s;                       // same 32 B region -> same line
}

// ---------------- K6: per-node softmax (no-max exp) + aggregation
// 1 wave / node; lane covers output features (lane, lane+64).
// Records read SEQUENTIALLY (32 B each); only Whp row gather is random.
__global__ __launch_bounds__(256) void aggregate_kernel(
    const int* __restrict__ rs, const uint32_t* __restrict__ rec,
    const uint32_t* __restrict__ Whp, float* __restrict__ out) {
  int node = blockIdx.x * 4 + (threadIdx.x >> 6);
  int lane = threadIdx.x & 63;
  int h1 = lane >> 4;       // head of feature `lane` (0..3)
  int start = rs[node], end = rs[node + 1];
  uint32_t sh = (h1 & 1) * 16;
  bool hi_pair = (h1 & 2) != 0;

  float z1 = 0.f, z2 = 0.f, a1 = 0.f, a2 = 0.f;

  #define STEP(g, wv)                                                  \
    {                                                                  \
      uint32_t c1 = hi_pair ? (g).y : (g).x;                           \
      uint32_t c2 = hi_pair ? (g).w : (g).z;                           \
      float l1 = __half2float(__ushort_as_half((uint16_t)(c1 >> sh))); \
      float l2 = __half2float(__ushort_as_half((uint16_t)(c2 >> sh))); \
      float e1 = __expf(l1), e2 = __expf(l2);                          \
      z1 += e1; z2 += e2;                                              \
      a1 += e1 * bflo(wv); a2 += e2 * bfhi(wv);                        \
    }

  int i = start;
  for (; i + 3 < end; i += 4) {
    const uint32_t* r0 = rec + (size_t)i * 8;
    uint4 g0 = *(const uint4*)(r0);
    uint4 g1 = *(const uint4*)(r0 + 8);
    uint4 g2 = *(const uint4*)(r0 + 16);
    uint4 g3 = *(const uint4*)(r0 + 24);
    int s0 = (int)r0[4], s1 = (int)r0[12], s2 = (int)r0[20], s3 = (int)r0[28];
    uint32_t w0 = Whp[(size_t)s0 * 64 + lane];
    uint32_t w1 = Whp[(size_t)s1 * 64 + lane];
    uint32_t w2 = Whp[(size_t)s2 * 64 + lane];
    uint32_t w3 = Whp[(size_t)s3 * 64 + lane];
    STEP(g0, w0); STEP(g1, w1); STEP(g2, w2); STEP(g3, w3);
  }
  for (; i < end; i++) {
    const uint32_t* r0 = rec + (size_t)i * 8;
    uint4 g0 = *(const uint4*)(r0);
    int s0 = (int)r0[4];
    uint32_t w0 = Whp[(size_t)s0 * 64 + lane];
    STEP(g0, w0);
  }
  #undef STEP

  float o1 = (end > start) ? a1 / z1 : 0.f;
  float o2 = (end > start) ? a2 / z2 : 0.f;
  out[(size_t)node * OUT_FEATS + lane] = o1;
  out[(size_t)node * OUT_FEATS + 64 + lane] = o2;
}

extern "C" void kernel_launch(void* const* d_in, const int* in_sizes, int n_in,
                              void* d_out, int out_size, void* d_ws, size_t ws_size,
                              hipStream_t stream) {
  const float* node_feats = (const float*)d_in[0];
  const float* edge_feats = (const float*)d_in[1];
  const int*   src        = (const int*)d_in[2];
  const int*   dst        = (const int*)d_in[3];
  const float* node_w     = (const float*)d_in[4];
  const float* node_b     = (const float*)d_in[5];
  const float* edge_w     = (const float*)d_in[6];
  const float* edge_b     = (const float*)d_in[7];
  const float* attn       = (const float*)d_in[8];
  float* out = (float*)d_out;

  char* ws = (char*)d_ws;
  size_t off = 0;
  auto alloc = [&](size_t bytes) {
    void* p = ws + off;
    off += (bytes + 255) & ~(size_t)255;
    return p;
  };
  uint32_t* Whp      = (uint32_t*)alloc((size_t)N_NODES * 64 * 4);      // 10.24 MB
  float*    s_src    = (float*)alloc((size_t)N_NODES * NUM_HEADS * 4);  // 1.28 MB
  float*    s_dst    = (float*)alloc((size_t)N_NODES * NUM_HEADS * 4);  // 1.28 MB
  uint32_t* rec      = (uint32_t*)alloc((size_t)N_EDGES * 32);          // 20.48 MB
  int*      deg      = (int*)alloc((size_t)N_NODES * 4);
  int*      rs       = (int*)alloc((size_t)(N_NODES + 1) * 4);
  int*      cursor   = (int*)alloc((size_t)N_NODES * 4);
  float*    Wfold    = (float*)alloc(NUM_HEADS * EDGE_FEATS * 4);
  float*    bfold    = (float*)alloc(NUM_HEADS * 4);
  uint32_t* Wbf      = (uint32_t*)alloc((size_t)OUT_FEATS * IN_FEATS * 2); // 64 KB

  hipMemsetAsync(deg, 0, (size_t)N_NODES * 4, stream);

  prep_hist_kernel<<<1 + N_EDGES / 512, 512, 0, stream>>>(
      edge_w, edge_b, attn, node_w, dst, Wfold, bfold, Wbf, deg);
  wh_gemm<<<N_NODES / 16 / 4, 256, 0, stream>>>(node_feats, Wbf, node_b, Whp);
  ssd_kernel<<<N_NODES * 4 / 256, 256, 0, stream>>>(Whp, attn, s_src, s_dst);
  scan_kernel<<<1, 1024, 0, stream>>>(deg, rs, cursor);
  edge_scatter_kernel<<<N_EDGES / 256, 256, 0, stream>>>(
      edge_feats, src, dst, Wfold, bfold, s_src, s_dst, cursor, rec);
  aggregate_kernel<<<N_NODES / 4, 256, 0, stream>>>(rs, rec, Whp, out);
}